// Round 4
// baseline (3814.071 us; speedup 1.0000x reference)
//
#include <hip/hip_runtime.h>

#define DEVINL __device__ __forceinline__

namespace {
constexpr int B = 256, T = 128, F = 128, H = 512;
constexpr int NBLK = 256;        // 1 batch row per block
constexpr int NTHR = 1024;       // 16 waves: 2 F-waves + 14 stream waves (soft roles)

// workspace layout in 4-byte words
constexpr size_t OFF_NUM    = 0;                         // [128] loss numerators
constexpr size_t OFF_DEN    = 128;                       // [128] denominators
constexpr size_t OFF_WQCC   = 256;                       // gates cc|m i8x4 [64 k4][2048 col]
constexpr size_t OFF_WQH    = OFF_WQCC + 64 * 2048;      // gates h    i8x4 [128 k4][2048 col]
constexpr size_t OFF_FSCC   = OFF_WQH + 128 * 2048;      // [2048] colmax/(127*15.875)
constexpr size_t OFF_FSCHG  = OFF_FSCC + 2048;           // [2048] colmax/16129
constexpr size_t OFF_HISTQ  = OFF_FSCHG + 2048;          // hist i8x4 [128 f][128 k4] ROW-major
constexpr size_t OFF_FSCH   = OFF_HISTQ + 128 * 128;     // [128] colmax/16129
constexpr size_t OFF_TD2    = OFF_FSCH + 128;            // td_h f16x2 [512 u][64 k2] ROW-major
constexpr size_t OFF_FEAT2  = OFF_TD2 + 64 * 512;        // feat f16x2 [128 f][64 k2] ROW-major
constexpr size_t OFF_WC2    = OFF_FEAT2 + 64 * 128;      // wc   f16x2 [128 f][128 k2] ROW-major
constexpr size_t OFF_BSUM   = OFF_WC2 + 128 * 128;       // [2048] b_ih+b_hh gate-interleaved
constexpr size_t OFF_FDIAG  = OFF_BSUM + 2048;           // [128] f16-rounded feat diag
constexpr size_t WS_WORDS   = OFF_FDIAG + 128;           // ~1.81 MB

constexpr float ACT_S  = 15.875f;                // cc|m activation scale (clamp +-8)
constexpr float DEQ_CC = 1.f / (127.f * 15.875f);
constexpr float DEQ_H  = 1.f / (127.f * 127.f);
}

typedef _Float16 h2_t __attribute__((ext_vector_type(2)));

DEVINL h2_t as_h2(unsigned u) { union { unsigned u; h2_t h; } c; c.u = u; return c.h; }
DEVINL unsigned pack2(float a, float b) {
  union { h2_t h; unsigned u; } c;
  c.h = h2_t{(_Float16)a, (_Float16)b};
  return c.u;
}
DEVINL unsigned pack4i(int a, int b, int c, int d) {
  return (a & 0xFF) | ((b & 0xFF) << 8) | ((c & 0xFF) << 16) | ((d & 0xFF) << 24);
}

#if defined(__has_builtin)
#if __has_builtin(__builtin_amdgcn_fdot2)
#define HAVE_FDOT2 1
#endif
#if __has_builtin(__builtin_amdgcn_sdot4)
#define HAVE_SDOT4 1
#endif
#endif
#ifdef HAVE_FDOT2
DEVINL float fdot2(h2_t a, h2_t b, float c) { return __builtin_amdgcn_fdot2(a, b, c, false); }
#else
DEVINL float fdot2(h2_t a, h2_t b, float c) {
  return fmaf((float)a.x, (float)b.x, fmaf((float)a.y, (float)b.y, c));
}
#endif
#ifdef HAVE_SDOT4
DEVINL int sdot4(int a, int b, int c) { return __builtin_amdgcn_sdot4(a, b, c, false); }
#else
DEVINL int sdot4(int a, int b, int c) {
  return c + ((a << 24) >> 24) * ((b << 24) >> 24)
           + ((a << 16) >> 24) * ((b << 16) >> 24)
           + ((a << 8) >> 24) * ((b << 8) >> 24)
           + (a >> 24) * (b >> 24);
}
#endif

DEVINL float fast_sig(float x)  { return 1.f / (1.f + __expf(-x)); }
DEVINL float fast_tanh(float x) { return 1.f - 2.f / (1.f + __expf(2.f * x)); }

DEVINL float wave_sum(float v) {
#pragma unroll
  for (int s = 32; s; s >>= 1) v += __shfl_down(v, s, 64);
  return v;
}
DEVINL float wave_max(float v) {
#pragma unroll
  for (int s = 32; s; s >>= 1) v = fmaxf(v, __shfl_down(v, s, 64));
  return v;
}

// ---- prep: f16 tables + biases (row-major per consumer) ----
__global__ void prep_f16(const float* __restrict__ td_h_W, const float* __restrict__ feat_W,
                         const float* __restrict__ wc_W, const float* __restrict__ b_ih,
                         const float* __restrict__ b_hh,
                         unsigned* __restrict__ wsu, float* __restrict__ wsf) {
  int idx = blockIdx.x * blockDim.x + threadIdx.x;
  if (idx < 32768) {                           // TD2 [512 u][64 k2]
    const int u = idx >> 6, k2 = idx & 63;
    wsu[OFF_TD2 + idx] = pack2(td_h_W[u * 128 + 2 * k2], td_h_W[u * 128 + 2 * k2 + 1]);
  } else if (idx < 40960) {                    // FEAT2 [128 f][64 k2]
    const int i = idx - 32768, f = i >> 6, k2 = i & 63;
    wsu[OFF_FEAT2 + i] = pack2(feat_W[f * 128 + 2 * k2], feat_W[f * 128 + 2 * k2 + 1]);
  } else if (idx < 57344) {                    // WC2 [128 f][128 k2]
    const int i = idx - 40960, f = i >> 7, k2 = i & 127;
    wsu[OFF_WC2 + i] = pack2(wc_W[f * 256 + 2 * k2], wc_W[f * 256 + 2 * k2 + 1]);
  } else if (idx < 59392) {                    // BSUM [2048]
    const int i = idx - 57344, unit = i >> 2, g = i & 3;
    wsf[OFF_BSUM + i] = b_ih[g * 512 + unit] + b_hh[g * 512 + unit];
  } else if (idx < 59520) {                    // FDIAG [128]
    const int f = idx - 59392;
    wsf[OFF_FDIAG + f] = (float)(_Float16)feat_W[f * 129];
  }
}

// ---- prep: i8 quant of W_ih columns (K=256, cc|m), per-column scale ----
__global__ void prep_quant_wih(const float* __restrict__ Wih,
                               unsigned* __restrict__ wq, float* __restrict__ fscc) {
  const int col = blockIdx.x;                  // 2048 = 4*unit+gate
  const int unit = col >> 2, g = col & 3;
  const float* src = Wih + (size_t)(g * 512 + unit) * 256;
  const int t = threadIdx.x;                   // 64 threads
  const float4 v = ((const float4*)src)[t];
  float mx = fmaxf(fmaxf(fabsf(v.x), fabsf(v.y)), fmaxf(fabsf(v.z), fabsf(v.w)));
  mx = wave_max(mx);
  mx = __shfl(mx, 0, 64);
  const float s = (mx > 0.f) ? 127.f / mx : 0.f;
  wq[t * 2048 + col] = pack4i(__float2int_rn(v.x * s), __float2int_rn(v.y * s),
                              __float2int_rn(v.z * s), __float2int_rn(v.w * s));
  if (t == 0) fscc[col] = mx * DEQ_CC;
}

// ---- prep: i8 quant of W_hh columns (K=512, h part) ----
__global__ void prep_quant_whh(const float* __restrict__ Whh,
                               unsigned* __restrict__ wq, float* __restrict__ fschg) {
  const int col = blockIdx.x;
  const int unit = col >> 2, g = col & 3;
  const float* src = Whh + (size_t)(g * 512 + unit) * 512;
  const int t = threadIdx.x;                   // 128 threads
  const float4 v = ((const float4*)src)[t];
  float mx = fmaxf(fmaxf(fabsf(v.x), fabsf(v.y)), fmaxf(fabsf(v.z), fabsf(v.w)));
  mx = wave_max(mx);
  __shared__ float wm[2];
  if ((t & 63) == 0) wm[t >> 6] = mx;
  __syncthreads();
  const float maxv = fmaxf(wm[0], wm[1]);
  const float s = (maxv > 0.f) ? 127.f / maxv : 0.f;
  wq[t * 2048 + col] = pack4i(__float2int_rn(v.x * s), __float2int_rn(v.y * s),
                              __float2int_rn(v.z * s), __float2int_rn(v.w * s));
  if (t == 0) fschg[col] = maxv * DEQ_H;
}

// ---- prep: i8 quant of hist_W rows (K=512), ROW-major [f][k4] ----
__global__ void prep_quant_hist(const float* __restrict__ histW,
                                unsigned* __restrict__ histq, float* __restrict__ fsch) {
  const int f = blockIdx.x;                    // 128
  const float* src = histW + (size_t)f * 512;
  const int t = threadIdx.x;                   // 128 threads
  const float4 v = ((const float4*)src)[t];
  float mx = fmaxf(fmaxf(fabsf(v.x), fabsf(v.y)), fmaxf(fabsf(v.z), fabsf(v.w)));
  mx = wave_max(mx);
  __shared__ float wm[2];
  if ((t & 63) == 0) wm[t >> 6] = mx;
  __syncthreads();
  const float maxv = fmaxf(wm[0], wm[1]);
  const float s = (maxv > 0.f) ? 127.f / maxv : 0.f;
  histq[f * 128 + t] = pack4i(__float2int_rn(v.x * s), __float2int_rn(v.y * s),
                              __float2int_rn(v.z * s), __float2int_rn(v.w * s));
  if (t == 0) fsch[f] = maxv * DEQ_H;
}

// stream work-queue item: j<2048 gates-h (unit=j&511, q=j>>9, k4 in [32q,32q+32));
// 2048<=j<2560 gates-ccm (unit=j-2048, k4 32..63); 2560<=j<2816 TD gamma(t+1) (2 units).
DEVINL void stream_job(int j, int parTD,
                       const unsigned* __restrict__ wsu, const float* __restrict__ td_h_b,
                       const unsigned* hq_s, const unsigned* actq_s, const unsigned* d2b_s,
                       float* gexp_s, int4* partH_s, int4* partCm_s) {
  if (j < 2048) {
    const int unit = j & 511, q = j >> 9;
    const unsigned* wp = wsu + OFF_WQH + 4 * unit + ((size_t)(32 * q) << 11);
    const unsigned* aw = hq_s + 32 * q;
    int4 acc{0, 0, 0, 0};
#pragma unroll 8
    for (int k = 0; k < 32; ++k) {
      const uint4 w = *(const uint4*)(wp + ((size_t)k << 11));
      const int a0 = (int)aw[k];
      acc.x = sdot4((int)w.x, a0, acc.x);
      acc.y = sdot4((int)w.y, a0, acc.y);
      acc.z = sdot4((int)w.z, a0, acc.z);
      acc.w = sdot4((int)w.w, a0, acc.w);
    }
    partH_s[q * 512 + unit] = acc;
  } else if (j < 2560) {
    const int unit = j - 2048;
    const unsigned* wp = wsu + OFF_WQCC + 4 * unit + ((size_t)32 << 11);
    const unsigned* aw = actq_s + 32;          // m half
    int4 acc{0, 0, 0, 0};
#pragma unroll 8
    for (int k = 0; k < 32; ++k) {
      const uint4 w = *(const uint4*)(wp + ((size_t)k << 11));
      const int a0 = (int)aw[k];
      acc.x = sdot4((int)w.x, a0, acc.x);
      acc.y = sdot4((int)w.y, a0, acc.y);
      acc.z = sdot4((int)w.z, a0, acc.z);
      acc.w = sdot4((int)w.w, a0, acc.w);
    }
    partCm_s[unit] = acc;
  } else {
    const int up = j - 2560;                   // unit pair
    const uint4* t0 = (const uint4*)(wsu + OFF_TD2 + (size_t)(2 * up) * 64);
    const uint4* dw = (const uint4*)(d2b_s + parTD * 64);
    float g0 = td_h_b[2 * up], g1 = td_h_b[2 * up + 1];
#pragma unroll 4
    for (int k = 0; k < 16; ++k) {
      const uint4 dd = dw[k];
      uint4 w = t0[k];
      g0 = fdot2(as_h2(w.x), as_h2(dd.x), g0);
      g0 = fdot2(as_h2(w.y), as_h2(dd.y), g0);
      g0 = fdot2(as_h2(w.z), as_h2(dd.z), g0);
      g0 = fdot2(as_h2(w.w), as_h2(dd.w), g0);
      w = t0[k + 16];
      g1 = fdot2(as_h2(w.x), as_h2(dd.x), g1);
      g1 = fdot2(as_h2(w.y), as_h2(dd.y), g1);
      g1 = fdot2(as_h2(w.z), as_h2(dd.z), g1);
      g1 = fdot2(as_h2(w.w), as_h2(dd.w), g1);
    }
    gexp_s[2 * up]     = __expf(-fmaxf(g0, 0.f));
    gexp_s[2 * up + 1] = __expf(-fmaxf(g1, 0.f));
  }
}

// ---- main: v0 skeleton, 4 barriers/step.
//  W1: [w0-1: x_hist full-K -> x_c -> pack] || [w2-15: 2 stream jobs]
//  W2: [w0-1: feat+alpha full-K -> outputs -> actq] || [w2-15: 1-2 stream jobs]
//  I : all: gates-cc half     FIN: LSTM + hq + stage(t+1)
__global__ void __launch_bounds__(NTHR) rits_batch(
    const float* __restrict__ x, const float* __restrict__ m, const float* __restrict__ d,
    const float* __restrict__ tx, const float* __restrict__ tmask,
    const float* __restrict__ td_h_b, const float* __restrict__ td_x_W,
    const float* __restrict__ td_x_b, const float* __restrict__ hist_b,
    const float* __restrict__ feat_b, const float* __restrict__ wc_b,
    const unsigned* __restrict__ wsu, const float* __restrict__ wsf,
    float* __restrict__ num, float* __restrict__ den, float* __restrict__ out)
{
  const int tid = threadIdx.x;
  const int row = blockIdx.x;
  const int st = tid - 128;                    // stream index (tid>=128)

  __shared__ __align__(16) unsigned hq_s[128];      // decayed-h i8 (scale 127)
  __shared__ __align__(16) unsigned actq_s[64];     // cc i8 0..31 | m i8 32..63
  __shared__ __align__(16) unsigned xc2_s[64];      // x_c f16 pairs
  __shared__ __align__(16) unsigned gxm2_s[128];    // gx pairs 0..63 | m pairs 64..127
  __shared__ __align__(16) unsigned d2b_s[128];     // d(t+1) f16 pairs, 2x64 parity
  __shared__ float x_s[128], m_s[128], tx_s[128], ev_s[128];
  __shared__ float dxw_s[128], dxb_s[128];
  __shared__ float gexp_s[512];                     // gamma_h exp for NEXT step
  __shared__ __align__(16) int4 partH_s[4 * 512];   // gates-h by k-quarter
  __shared__ __align__(16) int4 partCm_s[512];      // gates m-half
  __shared__ __align__(16) int4 partCc_s[2 * 512];  // gates cc-half by k-half

  // per-thread constants
  const int unit = tid & 511;
  const float4 bs    = *(const float4*)(wsf + OFF_BSUM + 4 * unit);
  const float4 fscc4 = *(const float4*)(wsf + OFF_FSCC + 4 * unit);
  const float4 fsch4 = *(const float4*)(wsf + OFF_FSCHG + 4 * unit);
  float hb = 0.f, fb = 0.f, wb = 0.f, fd = 0.f, fsf = 0.f;
  if (tid < 128) {
    hb = hist_b[tid]; fb = feat_b[tid]; wb = wc_b[tid];
    fd = wsf[OFF_FDIAG + tid]; fsf = wsf[OFF_FSCH + tid];
  }

  float h0 = 0.f, c0 = 0.f;                    // recurrent state (tid<512)

  // ---- prologue: tables + t=0 staging ----
  {
    const size_t b0 = (size_t)row * T * F;     // t=0
    if (tid < 128) {
      dxw_s[tid] = td_x_W[tid * 129];
      dxb_s[tid] = td_x_b[tid];
      hq_s[tid] = 0u;                          // h(0)=0
    } else if (tid < 160) {                    // m(0) i8 -> actq m-half
      const int w = tid - 128;
      const size_t b4 = b0 + 4 * w;
      actq_s[32 + w] = pack4i(__float2int_rn(m[b4] * ACT_S), __float2int_rn(m[b4 + 1] * ACT_S),
                              __float2int_rn(m[b4 + 2] * ACT_S), __float2int_rn(m[b4 + 3] * ACT_S));
    } else if (tid < 224) {                    // d(1) pairs -> d2b buffer 1
      const int j = tid - 160;
      d2b_s[64 + j] = pack2(d[b0 + F + 2 * j], d[b0 + F + 2 * j + 1]);
    } else if (tid >= 512) {                   // x/m/tx/ev rows t=0
      const int s3 = tid - 512, a = s3 >> 7, f2 = s3 & 127;
      const float v = (a == 0 ? x[b0 + f2] : a == 1 ? m[b0 + f2]
                       : a == 2 ? tx[b0 + f2] : tmask[b0 + f2]);
      if      (a == 0) x_s[f2]  = v;
      else if (a == 1) m_s[f2]  = v;
      else if (a == 2) tx_s[f2] = v;
      else             ev_s[f2] = v;
    }
    __syncthreads();
    if (tid < 64) {                            // gx(0) (needs dxw table)
      const float dv0 = d[b0 + 2 * tid], dv1 = d[b0 + 2 * tid + 1];
      const float g0 = __expf(-fmaxf(fmaf(dv0, dxw_s[2 * tid], dxb_s[2 * tid]), 0.f));
      const float g1 = __expf(-fmaxf(fmaf(dv1, dxw_s[2 * tid + 1], dxb_s[2 * tid + 1]), 0.f));
      gxm2_s[tid] = pack2(g0, g1);
    } else if (tid < 128) {                    // m(0) pairs
      const int j = tid - 64;
      gxm2_s[64 + j] = pack2(m[b0 + 2 * j], m[b0 + 2 * j + 1]);
    }
    __syncthreads();
  }

  for (int t = 0; t < T; ++t) {
    const size_t base = ((size_t)row * T + t) * F;
    const int parTD = (t + 1) & 1;
    float xh = 0.f, xc = 0.f;

    // ---- W1: x_hist chain (w0-1) || stream jobs 0..1791 ----
    if (tid < 128) {
      const int f = tid;
      int is = 0;
      const uint4* hw = (const uint4*)(wsu + OFF_HISTQ + (size_t)f * 128);
      const uint4* hq4 = (const uint4*)hq_s;
#pragma unroll 8
      for (int k = 0; k < 32; ++k) {
        const uint4 w = hw[k], a = hq4[k];
        is = sdot4((int)w.x, (int)a.x, is);
        is = sdot4((int)w.y, (int)a.y, is);
        is = sdot4((int)w.z, (int)a.z, is);
        is = sdot4((int)w.w, (int)a.w, is);
      }
      xh = fmaf((float)is, fsf, hb);
      const float mv = m_s[f], xv = x_s[f];
      xc = mv * xv + (1.f - mv) * xh;
      const float xcs = __shfl_down(xc, 1, 64);
      if (!(f & 1)) xc2_s[f >> 1] = pack2(xc, xcs);
    } else if (t < T - 1) {
      stream_job(st, parTD, wsu, td_h_b, hq_s, actq_s, d2b_s, gexp_s, partH_s, partCm_s);
      stream_job(st + 896, parTD, wsu, td_h_b, hq_s, actq_s, d2b_s, gexp_s, partH_s, partCm_s);
    }
    __syncthreads();   // S2

    // ---- W2: feat+alpha chain + outputs (w0-1) || stream jobs 1792..2815 ----
    if (tid < 128) {
      const int f = tid;
      float z = fb, aa = wb;
      {
        const uint4* fw = (const uint4*)(wsu + OFF_FEAT2 + (size_t)f * 64);
        const uint4* xw = (const uint4*)xc2_s;
#pragma unroll 8
        for (int k = 0; k < 16; ++k) {
          const uint4 w = fw[k], v = xw[k];
          z = fdot2(as_h2(w.x), as_h2(v.x), z);
          z = fdot2(as_h2(w.y), as_h2(v.y), z);
          z = fdot2(as_h2(w.z), as_h2(v.z), z);
          z = fdot2(as_h2(w.w), as_h2(v.w), z);
        }
        const uint4* ww = (const uint4*)(wsu + OFF_WC2 + (size_t)f * 128);
        const uint4* gw = (const uint4*)gxm2_s;
#pragma unroll 8
        for (int k = 0; k < 32; ++k) {
          const uint4 w = ww[k], g = gw[k];
          aa = fdot2(as_h2(w.x), as_h2(g.x), aa);
          aa = fdot2(as_h2(w.y), as_h2(g.y), aa);
          aa = fdot2(as_h2(w.z), as_h2(g.z), aa);
          aa = fdot2(as_h2(w.w), as_h2(g.w), aa);
        }
      }
      z -= xc * fd;                            // remove diagonal
      const float al = fast_sig(aa);
      const float ch = al * z + (1.f - al) * xh;
      const float mv = m_s[f], xv = x_s[f];
      const float cc = mv * xv + (1.f - mv) * ch;
      out[base + f] = cc;
      const float tg = tx_s[f], evv = ev_s[f];
      const float e1 = xh - tg, e2 = z - tg, e3 = ch - tg;
      const float s1 = wave_sum(evv * (e1 * e1 + e2 * e2 + e3 * e3));
      const float s2 = wave_sum(evv);
      if (!(tid & 63)) { atomicAdd(&num[t], s1); atomicAdd(&den[t], s2); }
      const int qc = __float2int_rn(fminf(fmaxf(cc, -8.f), 8.f) * ACT_S);
      const int c1 = __shfl_down(qc, 1, 64), c2 = __shfl_down(qc, 2, 64), c3 = __shfl_down(qc, 3, 64);
      if (!(f & 3)) actq_s[f >> 2] = pack4i(qc, c1, c2, c3);
    } else if (t < T - 1) {
      stream_job(1792 + st, parTD, wsu, td_h_b, hq_s, actq_s, d2b_s, gexp_s, partH_s, partCm_s);
      if (st < 128)
        stream_job(2688 + st, parTD, wsu, td_h_b, hq_s, actq_s, d2b_s, gexp_s, partH_s, partCm_s);
    }
    __syncthreads();   // S3

    if (t == T - 1) break;                     // outputs/loss complete

    // ---- I: gates cc-half (all 1024, k-split 2) ----
    {
      const int kh = tid >> 9;
      const unsigned* wp = wsu + OFF_WQCC + 4 * unit + ((size_t)(kh * 16) << 11);
      const unsigned* aw = actq_s + kh * 16;
      int4 acc{0, 0, 0, 0};
#pragma unroll 8
      for (int k = 0; k < 16; ++k) {
        const uint4 w = *(const uint4*)(wp + ((size_t)k << 11));
        const int a0 = (int)aw[k];
        acc.x = sdot4((int)w.x, a0, acc.x);
        acc.y = sdot4((int)w.y, a0, acc.y);
        acc.z = sdot4((int)w.z, a0, acc.z);
        acc.w = sdot4((int)w.w, a0, acc.w);
      }
      partCc_s[kh * 512 + unit] = acc;
    }
    __syncthreads();   // S4

    // ---- FIN: LSTM + hq(t+1) + stage(t+1); t <= 126 here ----
    if (tid < 512) {
      const int4 p0 = partH_s[unit], p1 = partH_s[512 + unit];
      const int4 p2 = partH_s[1024 + unit], p3 = partH_s[1536 + unit];
      const int4 cm = partCm_s[unit];
      const int4 q0 = partCc_s[unit], q1 = partCc_s[512 + unit];
      const float ai = bs.x + fscc4.x * (float)(cm.x + q0.x + q1.x)
                     + fsch4.x * (float)(p0.x + p1.x + p2.x + p3.x);
      const float af = bs.y + fscc4.y * (float)(cm.y + q0.y + q1.y)
                     + fsch4.y * (float)(p0.y + p1.y + p2.y + p3.y);
      const float ag = bs.z + fscc4.z * (float)(cm.z + q0.z + q1.z)
                     + fsch4.z * (float)(p0.z + p1.z + p2.z + p3.z);
      const float ao = bs.w + fscc4.w * (float)(cm.w + q0.w + q1.w)
                     + fsch4.w * (float)(p0.w + p1.w + p2.w + p3.w);
      const float ig = fast_sig(ai), fg = fast_sig(af);
      const float gg = fast_tanh(ag), og = fast_sig(ao);
      c0 = fg * c0 + ig * gg;
      h0 = og * fast_tanh(c0);
      // hq(t+1) = quant(h(t+1-) * gamma_h(t+1))  [gexp from TD jobs this step]
      const float hv = h0 * gexp_s[tid];
      int q = __float2int_rn(hv * 127.f);
      const int a1 = __shfl_down(q, 1, 64), a2 = __shfl_down(q, 2, 64), a3 = __shfl_down(q, 3, 64);
      if (!(tid & 3)) hq_s[tid >> 2] = pack4i(q, a1, a2, a3);
      // substaging for t+1 (valid: t+1 <= 127)
      const size_t b1 = base + F;
      if (tid < 64) {                          // gx(t+1)
        const float dv0 = d[b1 + 2 * tid], dv1 = d[b1 + 2 * tid + 1];
        const float g0 = __expf(-fmaxf(fmaf(dv0, dxw_s[2 * tid], dxb_s[2 * tid]), 0.f));
        const float g1 = __expf(-fmaxf(fmaf(dv1, dxw_s[2 * tid + 1], dxb_s[2 * tid + 1]), 0.f));
        gxm2_s[tid] = pack2(g0, g1);
      } else if (tid < 128) {                  // m(t+1) pairs
        const int j = tid - 64;
        gxm2_s[64 + j] = pack2(m[b1 + 2 * j], m[b1 + 2 * j + 1]);
      } else if (tid < 160) {                  // m(t+1) i8
        const int w = tid - 128;
        const size_t b4 = b1 + 4 * w;
        actq_s[32 + w] = pack4i(__float2int_rn(m[b4] * ACT_S), __float2int_rn(m[b4 + 1] * ACT_S),
                                __float2int_rn(m[b4 + 2] * ACT_S), __float2int_rn(m[b4 + 3] * ACT_S));
      } else if (tid < 224) {                  // d(t+2) pairs (for TD at step t+1)
        if (t + 2 < T) {
          const int j = tid - 160;
          const size_t b2 = base + 2 * F;
          d2b_s[((t + 2) & 1) * 64 + j] = pack2(d[b2 + 2 * j], d[b2 + 2 * j + 1]);
        }
      }
    } else {                                   // x/m/tx/ev rows for t+1
      const int s3 = tid - 512, a = s3 >> 7, f2 = s3 & 127;
      const size_t b1 = base + F;
      const float v = (a == 0 ? x[b1 + f2] : a == 1 ? m[b1 + f2]
                       : a == 2 ? tx[b1 + f2] : tmask[b1 + f2]);
      if      (a == 0) x_s[f2]  = v;
      else if (a == 1) m_s[f2]  = v;
      else if (a == 2) tx_s[f2] = v;
      else             ev_s[f2] = v;
    }
    __syncthreads();   // S1'
  }
}

__global__ void finalize(const float* __restrict__ num, const float* __restrict__ den,
                         float* __restrict__ out) {
  __shared__ float red[2];
  const int t = threadIdx.x;     // 128 threads
  float v = num[t] / (den[t] + 1e-8f);
  v = wave_sum(v);
  if ((t & 63) == 0) red[t >> 6] = v;
  __syncthreads();
  if (t == 0) out[(size_t)B * T * F] = (red[0] + red[1]) / (float)T;
}

extern "C" void kernel_launch(void* const* d_in, const int* in_sizes, int n_in,
                              void* d_out, int out_size, void* d_ws, size_t ws_size,
                              hipStream_t stream) {
  const float* x      = (const float*)d_in[0];
  const float* m      = (const float*)d_in[1];
  const float* d      = (const float*)d_in[2];
  const float* tx     = (const float*)d_in[3];
  const float* tmask  = (const float*)d_in[4];
  const float* td_h_W = (const float*)d_in[5];
  const float* td_h_b = (const float*)d_in[6];
  const float* td_x_W = (const float*)d_in[7];
  const float* td_x_b = (const float*)d_in[8];
  const float* hist_W = (const float*)d_in[9];
  const float* hist_b = (const float*)d_in[10];
  const float* feat_W = (const float*)d_in[11];
  const float* feat_b = (const float*)d_in[12];
  const float* wc_W   = (const float*)d_in[13];
  const float* wc_b   = (const float*)d_in[14];
  const float* W_ih   = (const float*)d_in[15];
  const float* W_hh   = (const float*)d_in[16];
  const float* b_ih   = (const float*)d_in[17];
  const float* b_hh   = (const float*)d_in[18];

  float*    wsf = (float*)d_ws;
  unsigned* wsu = (unsigned*)d_ws;
  float*    out = (float*)d_out;

  if (ws_size < WS_WORDS * 4) return;   // OOB tripwire

  hipMemsetAsync(d_ws, 0, 256 * sizeof(float), stream);   // num/den
  prep_f16<<<dim3((59520 + 255) / 256), dim3(256), 0, stream>>>(
      td_h_W, feat_W, wc_W, b_ih, b_hh, wsu, wsf);
  prep_quant_wih<<<dim3(2048), dim3(64), 0, stream>>>(
      W_ih, wsu + OFF_WQCC, wsf + OFF_FSCC);
  prep_quant_whh<<<dim3(2048), dim3(128), 0, stream>>>(
      W_hh, wsu + OFF_WQH, wsf + OFF_FSCHG);
  prep_quant_hist<<<dim3(128), dim3(128), 0, stream>>>(
      hist_W, wsu + OFF_HISTQ, wsf + OFF_FSCH);
  rits_batch<<<dim3(NBLK), dim3(NTHR), 0, stream>>>(
      x, m, d, tx, tmask, td_h_b, td_x_W, td_x_b, hist_b, feat_b, wc_b,
      wsu, wsf, wsf + OFF_NUM, wsf + OFF_DEN, out);
  finalize<<<dim3(1), dim3(128), 0, stream>>>(wsf + OFF_NUM, wsf + OFF_DEN, out);
}

// Round 5
// 3248.491 us; speedup vs baseline: 1.1741x; 1.1741x over previous
//
#include <hip/hip_runtime.h>

#define DEVINL __device__ __forceinline__

namespace {
constexpr int B = 256, T = 128, F = 128, H = 512;
constexpr int NBLK = 256;        // 1 batch row per block, all 256 CUs active
constexpr int NTHR = 1024;       // 16 waves

// workspace layout in 4-byte words (v0, TD2 now ROW-major [512 u][64 k2])
constexpr size_t OFF_NUM    = 0;                         // [128] loss numerators
constexpr size_t OFF_DEN    = 128;                       // [128] denominators
constexpr size_t OFF_WQCC   = 256;                       // gates cc|m i8x4 [64 k4][2048 col]
constexpr size_t OFF_WQH    = OFF_WQCC + 64 * 2048;      // gates h    i8x4 [128 k4][2048 col]
constexpr size_t OFF_FSCC   = OFF_WQH + 128 * 2048;      // [2048] colmax/(127*15.875)
constexpr size_t OFF_FSCHG  = OFF_FSCC + 2048;           // [2048] colmax/16129
constexpr size_t OFF_HISTQ  = OFF_FSCHG + 2048;          // hist i8x4 [128 k4][128 f] col-major
constexpr size_t OFF_FSCH   = OFF_HISTQ + 128 * 128;     // [128] colmax/16129
constexpr size_t OFF_TD2    = OFF_FSCH + 128;            // td_h f16x2 [512 u][64 k2] ROW-major
constexpr size_t OFF_FEAT2  = OFF_TD2 + 64 * 512;        // feat f16x2 [64 k2][128 f]
constexpr size_t OFF_WC2    = OFF_FEAT2 + 64 * 128;      // wc   f16x2 [128 k2][128 f]
constexpr size_t OFF_BSUM   = OFF_WC2 + 128 * 128;       // [2048] b_ih+b_hh gate-interleaved
constexpr size_t OFF_FDIAG  = OFF_BSUM + 2048;           // [128] f16-rounded feat diag
constexpr size_t WS_WORDS   = OFF_FDIAG + 128;           // ~1.81 MB

constexpr float ACT_S  = 15.875f;                // cc|m activation scale (clamp +-8)
constexpr float DEQ_CC = 1.f / (127.f * 15.875f);
constexpr float DEQ_H  = 1.f / (127.f * 127.f);
}

typedef _Float16 h2_t __attribute__((ext_vector_type(2)));

DEVINL h2_t as_h2(unsigned u) { union { unsigned u; h2_t h; } c; c.u = u; return c.h; }
DEVINL unsigned pack2(float a, float b) {
  union { h2_t h; unsigned u; } c;
  c.h = h2_t{(_Float16)a, (_Float16)b};
  return c.u;
}
DEVINL unsigned pack4i(int a, int b, int c, int d) {
  return (a & 0xFF) | ((b & 0xFF) << 8) | ((c & 0xFF) << 16) | ((d & 0xFF) << 24);
}

#if defined(__has_builtin)
#if __has_builtin(__builtin_amdgcn_fdot2)
#define HAVE_FDOT2 1
#endif
#if __has_builtin(__builtin_amdgcn_sdot4)
#define HAVE_SDOT4 1
#endif
#endif
#ifdef HAVE_FDOT2
DEVINL float fdot2(h2_t a, h2_t b, float c) { return __builtin_amdgcn_fdot2(a, b, c, false); }
#else
DEVINL float fdot2(h2_t a, h2_t b, float c) {
  return fmaf((float)a.x, (float)b.x, fmaf((float)a.y, (float)b.y, c));
}
#endif
#ifdef HAVE_SDOT4
DEVINL int sdot4(int a, int b, int c) { return __builtin_amdgcn_sdot4(a, b, c, false); }
#else
DEVINL int sdot4(int a, int b, int c) {
  return c + ((a << 24) >> 24) * ((b << 24) >> 24)
           + ((a << 16) >> 24) * ((b << 16) >> 24)
           + ((a << 8) >> 24) * ((b << 8) >> 24)
           + (a >> 24) * (b >> 24);
}
#endif

DEVINL float fast_sig(float x)  { return 1.f / (1.f + __expf(-x)); }
DEVINL float fast_tanh(float x) { return 1.f - 2.f / (1.f + __expf(2.f * x)); }

DEVINL float wave_sum(float v) {
#pragma unroll
  for (int s = 32; s; s >>= 1) v += __shfl_down(v, s, 64);
  return v;
}
DEVINL float wave_max(float v) {
#pragma unroll
  for (int s = 32; s; s >>= 1) v = fmaxf(v, __shfl_down(v, s, 64));
  return v;
}

// ---- prep: f16 tables + biases (TD2 ROW-major; FEAT2/WC2 col-major as v0) ----
__global__ void prep_f16(const float* __restrict__ td_h_W, const float* __restrict__ feat_W,
                         const float* __restrict__ wc_W, const float* __restrict__ b_ih,
                         const float* __restrict__ b_hh,
                         unsigned* __restrict__ wsu, float* __restrict__ wsf) {
  int idx = blockIdx.x * blockDim.x + threadIdx.x;
  if (idx < 32768) {                           // TD2 [512 u][64 k2] ROW-major
    const int u = idx >> 6, k2 = idx & 63;
    wsu[OFF_TD2 + idx] = pack2(td_h_W[u * 128 + 2 * k2], td_h_W[u * 128 + 2 * k2 + 1]);
  } else if (idx < 40960) {                    // FEAT2 [64 k2][128 f]
    const int i = idx - 32768, k2 = i >> 7, f = i & 127;
    wsu[OFF_FEAT2 + i] = pack2(feat_W[f * 128 + 2 * k2], feat_W[f * 128 + 2 * k2 + 1]);
  } else if (idx < 57344) {                    // WC2 [128 k2][128 f]
    const int i = idx - 40960, k2 = i >> 7, f = i & 127;
    wsu[OFF_WC2 + i] = pack2(wc_W[f * 256 + 2 * k2], wc_W[f * 256 + 2 * k2 + 1]);
  } else if (idx < 59392) {                    // BSUM [2048]
    const int i = idx - 57344, unit = i >> 2, g = i & 3;
    wsf[OFF_BSUM + i] = b_ih[g * 512 + unit] + b_hh[g * 512 + unit];
  } else if (idx < 59520) {                    // FDIAG [128]
    const int f = idx - 59392;
    wsf[OFF_FDIAG + f] = (float)(_Float16)feat_W[f * 129];
  }
}

// ---- prep: i8 quant of W_ih columns (K=256, cc|m part), per-column scale ----
__global__ void prep_quant_wih(const float* __restrict__ Wih,
                               unsigned* __restrict__ wq, float* __restrict__ fscc) {
  const int col = blockIdx.x;                  // 2048 = 4*unit+gate
  const int unit = col >> 2, g = col & 3;
  const float* src = Wih + (size_t)(g * 512 + unit) * 256;
  const int t = threadIdx.x;                   // 64 threads (one wave), 4 k each
  const float4 v = ((const float4*)src)[t];
  float mx = fmaxf(fmaxf(fabsf(v.x), fabsf(v.y)), fmaxf(fabsf(v.z), fabsf(v.w)));
  mx = wave_max(mx);
  mx = __shfl(mx, 0, 64);
  const float s = (mx > 0.f) ? 127.f / mx : 0.f;
  wq[t * 2048 + col] = pack4i(__float2int_rn(v.x * s), __float2int_rn(v.y * s),
                              __float2int_rn(v.z * s), __float2int_rn(v.w * s));
  if (t == 0) fscc[col] = mx * DEQ_CC;
}

// ---- prep: i8 quant of W_hh columns (K=512, h part) ----
__global__ void prep_quant_whh(const float* __restrict__ Whh,
                               unsigned* __restrict__ wq, float* __restrict__ fschg) {
  const int col = blockIdx.x;
  const int unit = col >> 2, g = col & 3;
  const float* src = Whh + (size_t)(g * 512 + unit) * 512;
  const int t = threadIdx.x;                   // 128 threads, 4 k each
  const float4 v = ((const float4*)src)[t];
  float mx = fmaxf(fmaxf(fabsf(v.x), fabsf(v.y)), fmaxf(fabsf(v.z), fabsf(v.w)));
  mx = wave_max(mx);
  __shared__ float wm[2];
  if ((t & 63) == 0) wm[t >> 6] = mx;
  __syncthreads();
  const float maxv = fmaxf(wm[0], wm[1]);
  const float s = (maxv > 0.f) ? 127.f / maxv : 0.f;
  wq[t * 2048 + col] = pack4i(__float2int_rn(v.x * s), __float2int_rn(v.y * s),
                              __float2int_rn(v.z * s), __float2int_rn(v.w * s));
  if (t == 0) fschg[col] = maxv * DEQ_H;
}

// ---- prep: i8 quant of hist_W rows (K=512), col-major [k4][f] as v0 ----
__global__ void prep_quant_hist(const float* __restrict__ histW,
                                unsigned* __restrict__ histq, float* __restrict__ fsch) {
  const int f = blockIdx.x;                    // 128
  const float* src = histW + (size_t)f * 512;
  const int t = threadIdx.x;                   // 128 threads
  const float4 v = ((const float4*)src)[t];
  float mx = fmaxf(fmaxf(fabsf(v.x), fabsf(v.y)), fmaxf(fabsf(v.z), fabsf(v.w)));
  mx = wave_max(mx);
  __shared__ float wm[2];
  if ((t & 63) == 0) wm[t >> 6] = mx;
  __syncthreads();
  const float maxv = fmaxf(wm[0], wm[1]);
  const float s = (maxv > 0.f) ? 127.f / maxv : 0.f;
  histq[t * 128 + f] = pack4i(__float2int_rn(v.x * s), __float2int_rn(v.y * s),
                              __float2int_rn(v.z * s), __float2int_rn(v.w * s));
  if (t == 0) fsch[f] = maxv * DEQ_H;
}

// ---- main: v0 structure minus phase C. Per step:
//      A | E | E' | G | G' | atomic(+break at T-1) | I(+TD prefetch)+LSTM+hq ----
__global__ void __launch_bounds__(1024) rits_batch(
    const float* __restrict__ x, const float* __restrict__ m, const float* __restrict__ d,
    const float* __restrict__ tx, const float* __restrict__ tmask,
    const float* __restrict__ td_h_b, const float* __restrict__ td_x_W,
    const float* __restrict__ td_x_b, const float* __restrict__ hist_b,
    const float* __restrict__ feat_b, const float* __restrict__ wc_b,
    const unsigned* __restrict__ wsu, const float* __restrict__ wsf,
    float* __restrict__ num, float* __restrict__ den, float* __restrict__ out)
{
  const int tid = threadIdx.x;
  const int row = blockIdx.x;
  const int unit = tid & 511;                  // phase I unit
  const int kh = tid >> 9;                     // phase I k-half

  __shared__ __align__(16) unsigned actq[64];  // cc i8 words 0..31 | m i8 32..63
  __shared__ __align__(16) int hq[128];        // decayed h i8 (scale 127)
  __shared__ __align__(16) unsigned d2b[128];  // d(t+1) f16 pairs, 2x64 parity
  __shared__ __align__(16) unsigned xc2[64];   // x_c f16 pairs
  __shared__ __align__(16) unsigned gxm2[128]; // gx pairs 0..63 | m pairs 64..127
  __shared__ float xrow[128], mrow[128], drow[128], txrow[128], evrow[128];
  __shared__ int   partI[1024];                // x_hist K-split partials
  __shared__ float partZ[1024], partA[1024];   // feat / alpha partials
  __shared__ __align__(16) int4 partHc[512], partHh[512];   // gates partials (upper k-half)
  __shared__ float gexp_s[512];                // exp(-relu(td.d(t+1))) prefetched in I
  __shared__ float redA[2], redB[2];

  // persistent per-thread constants (v0)
  const float4 bs    = *(const float4*)(wsf + OFF_BSUM + 4 * unit);
  const float4 fscc4 = *(const float4*)(wsf + OFF_FSCC + 4 * unit);
  const float4 fsch4 = *(const float4*)(wsf + OFF_FSCHG + 4 * unit);
  const float tdb = td_h_b[unit];
  const int fc = tid & 127;
  const float hb = hist_b[fc], fb = feat_b[fc], wb = wc_b[fc];
  const float fd = wsf[OFF_FDIAG + fc];
  const float dxw = td_x_W[fc * 129], dxb = td_x_b[fc];
  const float fsch_f = wsf[OFF_FSCH + fc];

  float h0 = 0.f, c0 = 0.f;                    // recurrent state (tid<512)
  if (tid < 128) hq[tid] = 0;                  // h(0)=0 -> hq(0)=0 (visible after S1)

  for (int t = 0; t < T; ++t) {
    const int base = (row * T + t) * F;
    float xh_r = 0.f, xc_r = 0.f;              // live E' -> G' (tid<128)

    // ---- A: stage this step's input row ----
    if (tid < 640) {
      const int a = tid >> 7, f = tid & 127;
      const float v = (a == 0 ? x[base + f] : a == 1 ? m[base + f] : a == 2 ? d[base + f]
                       : a == 3 ? tx[base + f] : tmask[base + f]);
      if      (a == 0) xrow[f]  = v;
      else if (a == 1) mrow[f]  = v;
      else if (a == 2) drow[f]  = v;
      else if (a == 3) txrow[f] = v;
      else             evrow[f] = v;
    } else if (tid < 704) {
      if (t < T - 1) {                         // d(t+1) pairs for TD prefetch in I
        const int k2 = tid - 640;
        d2b[((t + 1) & 1) * 64 + k2] = pack2(d[base + F + 2 * k2], d[base + F + 2 * k2 + 1]);
      }
    } else if (tid < 768) {
      const int q = tid - 704;
      gxm2[64 + q] = pack2(m[base + 2 * q], m[base + 2 * q + 1]);
    } else if (tid < 800) {
      const int w = tid - 768;
      const int b4 = base + 4 * w;
      actq[32 + w] = pack4i(__float2int_rn(m[b4] * ACT_S), __float2int_rn(m[b4 + 1] * ACT_S),
                            __float2int_rn(m[b4 + 2] * ACT_S), __float2int_rn(m[b4 + 3] * ACT_S));
    }
    __syncthreads();   // S1

    // ---- E: x_hist partials (i8, K split 8 ways over all 16 waves) ----
    {
      const int kq = tid >> 7;
      int isum = 0;
#pragma unroll 8
      for (int k = 0; k < 16; ++k) {
        const int k4 = kq * 16 + k;
        isum = sdot4((int)wsu[OFF_HISTQ + (k4 << 7) + fc], hq[k4], isum);
      }
      partI[tid] = isum;
    }
    __syncthreads();   // S2

    // ---- E': reduce x_hist; gamma_x; x_c; pack xc2/gx pairs ----
    if (tid < 128) {
      int isum = 0;
#pragma unroll
      for (int i = 0; i < 8; ++i) isum += partI[tid + 128 * i];
      xh_r = fmaf((float)isum, fsch_f, hb);
      const float gx = __expf(-fmaxf(fmaf(drow[tid], dxw, dxb), 0.f));
      const float mv = mrow[tid];
      xc_r = mv * xrow[tid] + (1.f - mv) * xh_r;
      const float xcs = __shfl_down(xc_r, 1, 64);
      const float gxs = __shfl_down(gx, 1, 64);
      if (!(tid & 1)) {
        xc2[tid >> 1]  = pack2(xc_r, xcs);
        gxm2[tid >> 1] = pack2(gx, gxs);
      }
    }
    __syncthreads();   // S3

    // ---- G: feat + alpha partials (f16, K split 8 ways) ----
    {
      const int kq = tid >> 7;
      float zs = 0.f;
#pragma unroll 8
      for (int k = 0; k < 8; ++k) {
        const int k2 = kq * 8 + k;
        zs = fdot2(as_h2(wsu[OFF_FEAT2 + (k2 << 7) + fc]), as_h2(xc2[k2]), zs);
      }
      partZ[tid] = zs;
      float as = 0.f;
#pragma unroll 8
      for (int k = 0; k < 16; ++k) {
        const int k2 = kq * 16 + k;
        as = fdot2(as_h2(wsu[OFF_WC2 + (k2 << 7) + fc]), as_h2(gxm2[k2]), as);
      }
      partA[tid] = as;
    }
    __syncthreads();   // S4

    // ---- G': z_h, alpha, c_h, c_c, out, loss partials, pack cc -> i8 ----
    if (tid < 128) {
      float z = fb, aa = wb;
#pragma unroll
      for (int i = 0; i < 8; ++i) { z += partZ[tid + 128 * i]; aa += partA[tid + 128 * i]; }
      z -= xc_r * fd;                          // remove diagonal
      const float al = fast_sig(aa);
      const float ch = al * z + (1.f - al) * xh_r;
      const float mv = mrow[tid];
      const float cc = mv * xrow[tid] + (1.f - mv) * ch;
      out[base + tid] = cc;
      const float ev = evrow[tid], tg = txrow[tid];
      const float e1 = xh_r - tg, e2 = z - tg, e3 = ch - tg;
      const float s1 = wave_sum(ev * (e1 * e1 + e2 * e2 + e3 * e3));
      const float s2 = wave_sum(ev);
      if ((tid & 63) == 0) { redA[tid >> 6] = s1; redB[tid >> 6] = s2; }
      int qc = __float2int_rn(fminf(fmaxf(cc, -8.f), 8.f) * ACT_S);
      const int c1s = __shfl_down(qc, 1, 64), c2s = __shfl_down(qc, 2, 64), c3s = __shfl_down(qc, 3, 64);
      if (!(tid & 3)) actq[tid >> 2] = pack4i(qc, c1s, c2s, c3s);
    }
    __syncthreads();   // S5

    if (tid == 1023) {
      atomicAdd(&num[t], redA[0] + redA[1]);
      atomicAdd(&den[t], redB[0] + redB[1]);
    }
    if (t == T - 1) break;                     // outputs/loss done; skip dead gates sweep

    // ---- I: gates partials (K split 2) + TD(t+1) prefetch + LSTM + hq(t+1) ----
    {
      int ci = 0, cf = 0, cg = 0, co = 0;
      const unsigned* wq = wsu + OFF_WQCC + 4 * unit;
#pragma unroll 8
      for (int k = 0; k < 32; ++k) {
        const int k4 = kh * 32 + k;
        const uint4 w = *(const uint4*)(wq + (k4 << 11));
        const int a0 = (int)actq[k4];
        ci = sdot4((int)w.x, a0, ci); cf = sdot4((int)w.y, a0, cf);
        cg = sdot4((int)w.z, a0, cg); co = sdot4((int)w.w, a0, co);
      }
      int hi = 0, hf = 0, hg = 0, ho = 0;
      const unsigned* wh = wsu + OFF_WQH + 4 * unit;
#pragma unroll 8
      for (int k = 0; k < 64; ++k) {
        const int k4 = kh * 64 + k;
        const uint4 w = *(const uint4*)(wh + (k4 << 11));
        const int a0 = hq[k4];
        hi = sdot4((int)w.x, a0, hi); hf = sdot4((int)w.y, a0, hf);
        hg = sdot4((int)w.z, a0, hg); ho = sdot4((int)w.w, a0, ho);
      }
      if (tid >= 512) {
        partHc[unit] = int4{ci, cf, cg, co};
        partHh[unit] = int4{hi, hf, hg, ho};
        // TD prefetch: gamma_h(t+1) for this unit (row-major TD2, uint4 loads)
        float g0 = tdb;
        const uint4* tw = (const uint4*)(wsu + OFF_TD2 + (size_t)unit * 64);
        const uint4* dw = (const uint4*)(d2b + ((t + 1) & 1) * 64);
#pragma unroll 4
        for (int q = 0; q < 16; ++q) {
          const uint4 w = tw[q], dd = dw[q];
          g0 = fdot2(as_h2(w.x), as_h2(dd.x), g0);
          g0 = fdot2(as_h2(w.y), as_h2(dd.y), g0);
          g0 = fdot2(as_h2(w.z), as_h2(dd.z), g0);
          g0 = fdot2(as_h2(w.w), as_h2(dd.w), g0);
        }
        gexp_s[unit] = __expf(-fmaxf(g0, 0.f));
      }
      __syncthreads();   // S6 (inner)
      if (tid < 512) {
        const int4 pc = partHc[unit], ph = partHh[unit];
        const float ai = bs.x + fscc4.x * (float)(ci + pc.x) + fsch4.x * (float)(hi + ph.x);
        const float af = bs.y + fscc4.y * (float)(cf + pc.y) + fsch4.y * (float)(hf + ph.y);
        const float ag = bs.z + fscc4.z * (float)(cg + pc.z) + fsch4.z * (float)(hg + ph.z);
        const float ao = bs.w + fscc4.w * (float)(co + pc.w) + fsch4.w * (float)(ho + ph.w);
        const float ig = fast_sig(ai), fg = fast_sig(af);
        const float gg = fast_tanh(ag), og = fast_sig(ao);
        c0 = fg * c0 + ig * gg;
        h0 = og * fast_tanh(c0);
        // hq(t+1) = quant(h_new * gamma_h(t+1))  [gexp from TD prefetch above]
        const float hv = h0 * gexp_s[unit];
        int q = __float2int_rn(hv * 127.f);
        const int a1 = __shfl_down(q, 1, 64), a2 = __shfl_down(q, 2, 64), a3 = __shfl_down(q, 3, 64);
        if (!(tid & 3)) hq[tid >> 2] = pack4i(q, a1, a2, a3);
      }
    }
    __syncthreads();   // S7: protect hq/actq/rows/partials for next step
  }
}

__global__ void finalize(const float* __restrict__ num, const float* __restrict__ den,
                         float* __restrict__ out) {
  __shared__ float red[2];
  const int t = threadIdx.x;     // 128 threads
  float v = num[t] / (den[t] + 1e-8f);
  v = wave_sum(v);
  if ((t & 63) == 0) red[t >> 6] = v;
  __syncthreads();
  if (t == 0) out[(size_t)B * T * F] = (red[0] + red[1]) / (float)T;
}

extern "C" void kernel_launch(void* const* d_in, const int* in_sizes, int n_in,
                              void* d_out, int out_size, void* d_ws, size_t ws_size,
                              hipStream_t stream) {
  const float* x      = (const float*)d_in[0];
  const float* m      = (const float*)d_in[1];
  const float* d      = (const float*)d_in[2];
  const float* tx     = (const float*)d_in[3];
  const float* tmask  = (const float*)d_in[4];
  const float* td_h_W = (const float*)d_in[5];
  const float* td_h_b = (const float*)d_in[6];
  const float* td_x_W = (const float*)d_in[7];
  const float* td_x_b = (const float*)d_in[8];
  const float* hist_W = (const float*)d_in[9];
  const float* hist_b = (const float*)d_in[10];
  const float* feat_W = (const float*)d_in[11];
  const float* feat_b = (const float*)d_in[12];
  const float* wc_W   = (const float*)d_in[13];
  const float* wc_b   = (const float*)d_in[14];
  const float* W_ih   = (const float*)d_in[15];
  const float* W_hh   = (const float*)d_in[16];
  const float* b_ih   = (const float*)d_in[17];
  const float* b_hh   = (const float*)d_in[18];

  float*    wsf = (float*)d_ws;
  unsigned* wsu = (unsigned*)d_ws;
  float*    out = (float*)d_out;

  if (ws_size < WS_WORDS * 4) return;   // OOB tripwire

  hipMemsetAsync(d_ws, 0, 256 * sizeof(float), stream);   // num/den
  prep_f16<<<dim3((59520 + 255) / 256), dim3(256), 0, stream>>>(
      td_h_W, feat_W, wc_W, b_ih, b_hh, wsu, wsf);
  prep_quant_wih<<<dim3(2048), dim3(64), 0, stream>>>(
      W_ih, wsu + OFF_WQCC, wsf + OFF_FSCC);
  prep_quant_whh<<<dim3(2048), dim3(128), 0, stream>>>(
      W_hh, wsu + OFF_WQH, wsf + OFF_FSCHG);
  prep_quant_hist<<<dim3(128), dim3(128), 0, stream>>>(
      hist_W, wsu + OFF_HISTQ, wsf + OFF_FSCH);
  rits_batch<<<dim3(NBLK), dim3(NTHR), 0, stream>>>(
      x, m, d, tx, tmask, td_h_b, td_x_W, td_x_b, hist_b, feat_b, wc_b,
      wsu, wsf, wsf + OFF_NUM, wsf + OFF_DEN, out);
  finalize<<<dim3(1), dim3(128), 0, stream>>>(wsf + OFF_NUM, wsf + OFF_DEN, out);
}